// Round 6
// baseline (111.532 us; speedup 1.0000x reference)
//
#include <hip/hip_runtime.h>

#define B 256
#define K 32
#define M 64
#define MN 256
#define E 128
#define H 128
#define Q 128
#define NSLOT 258   // NNODES+2
#define CTILE 32
#define XPAD 392    // 384 + 8 bf16 pad

typedef __attribute__((ext_vector_type(8))) short short8;
typedef __attribute__((ext_vector_type(4))) short short4b;
typedef __attribute__((ext_vector_type(4))) float f32x4;

__device__ __forceinline__ float lrelu(float x){ return x >= 0.f ? x : 0.01f*x; }

// fp32 -> bf16 RTNE
__device__ __forceinline__ unsigned short f2bf(float f){
    unsigned int u = __float_as_uint(f);
    unsigned int r = u + 0x7FFFu + ((u >> 16) & 1u);
    return (unsigned short)(r >> 16);
}

__device__ __forceinline__ short4b pack4(float4 v){
    short4b r;
    r.x = (short)f2bf(v.x); r.y = (short)f2bf(v.y);
    r.z = (short)f2bf(v.z); r.w = (short)f2bf(v.w);
    return r;
}

// =====================================================================
// K_A: fused gather + prep. grid = B*K blocks (8192), 256 threads.
//  every block: neighbor gather for (b,k) -> Xg row, ab
//  k==0 block:  init[b] + wninit[b] (LDS-tiled matvecs)
//  k==1 block:  Wf swizzle-convert slice  (candidate_W -> MFMA frag order)
//  k==2 block:  Wcat_f swizzle-convert slice ([passW[:,H:]|hW] -> frag order)
//  k==3 block:  map[b]
// =====================================================================
__global__ void k_gprep(const int* __restrict__ aims, const int* __restrict__ nbr_nodes,
                        const int* __restrict__ nbr_rels, const int* __restrict__ nbr_num,
                        const int* __restrict__ start_ent, const int* __restrict__ node_pos,
                        const float* __restrict__ ent_emb, const float* __restrict__ rel_emb,
                        const float* __restrict__ hW, const float* __restrict__ hb,
                        const float* __restrict__ passW, const float* __restrict__ candW,
                        unsigned short* __restrict__ Xg, float* __restrict__ ab,
                        int* __restrict__ map,
                        float* __restrict__ init_out, float* __restrict__ wninit_out,
                        unsigned short* __restrict__ Wf, unsigned short* __restrict__ Wcatf){
    int bk = blockIdx.x;
    int b = bk >> 5, k = bk & 31;
    int t = threadIdx.x;          // 0..255
    int num = nbr_num[bk];
    __shared__ int sidx[M];
    __shared__ int sc0;
    __shared__ float red[8][128];
    __shared__ float e[128], si[128];
    __shared__ float wt[128][33];

    // ---------------- gather phase (all blocks) ----------------
    if (t < 64) sidx[t] = nbr_rels[(long)bk*M + t];
    if (t >= 64 && t < 128) {     // wave 1
        int m = t - 64;
        bool flag = (m < num) && (nbr_nodes[(long)bk*M + m] == 0);
        unsigned long long mask = __ballot(flag);
        if (m == 0) sc0 = (int)__popcll(mask);
    }
    if (t >= 128) {               // waves 2,3: aim entity row -> X[128..255]
        int d = t - 128;
        Xg[(long)bk*256 + 128 + d] = f2bf(ent_emb[(long)aims[bk]*E + d]);
    }
    __syncthreads();
    {
        int mg = t >> 5, q = t & 31;
        float4 acc = {0.f,0.f,0.f,0.f};
        for (int m = mg; m < num; m += 8) {
            const float4 v = *(const float4*)&rel_emb[(long)sidx[m]*E + q*4];
            acc.x += v.x; acc.y += v.y; acc.z += v.z; acc.w += v.w;
        }
        red[mg][q*4+0] = acc.x; red[mg][q*4+1] = acc.y;
        red[mg][q*4+2] = acc.z; red[mg][q*4+3] = acc.w;
    }
    __syncthreads();
    float denom = (float)(num > 0 ? num : 1);
    if (t < 128) {
        float s = 0.f;
        #pragma unroll
        for (int g=0; g<8; g++) s += red[g][t];
        Xg[(long)bk*256 + t] = f2bf(s / denom);
    }
    if (t == 0) {
        ab[bk*2+0] = (float)sc0 / denom;
        ab[bk*2+1] = (float)num / denom;
    }

    // ---------------- side duties by k ----------------
    if (k == 1) {
        // Wf: 49152 elems total, 192 per block.
        // layout: i = ((w*12+ks)<<10) | (ct<<9) | (lane<<3) | j
        if (t < 192) {
            int i = b*192 + t;
            int j = i & 7;
            int l = (i >> 3) & 63;
            int ct = (i >> 9) & 1;
            int r = i >> 10;
            int ks = r % 12, w = r / 12;
            int row = w*32 + ct*16 + (l & 15);
            int col = ks*32 + (l >> 4)*8 + j;
            Wf[i] = f2bf(candW[row*384 + col]);
        }
    } else if (k == 2) {
        // Wcat_f: 32768 elems, 128 per block. Wcat[h][c] = c<128 ? passW[h][128+c] : hW[h][c-128]
        if (t < 128) {
            int i = b*128 + t;
            int j = i & 7;
            int l = (i >> 3) & 63;
            int ct = (i >> 9) & 1;
            int r = i >> 10;
            int ks = r & 7, w = r >> 3;
            int row = w*32 + ct*16 + (l & 15);
            int col = ks*32 + (l >> 4)*8 + j;
            float v = (col < 128) ? passW[row*256 + 128 + col] : hW[row*128 + (col-128)];
            Wcatf[i] = f2bf(v);
        }
    } else if (k == 3) {
        for (int i=t;i<NSLOT;i+=256) map[b*NSLOT+i] = -2;
        __syncthreads();
        if (t==0) map[b*NSLOT+0] = -1;
        if (t<K) map[b*NSLOT + node_pos[b*K+t]] = t;   // node_pos in 1..K, disjoint from 0
    } else if (k == 0) {
        // init = lrelu(hW @ e + hb); wninit = passW[:, :H] @ init  (LDS-tiled)
        if (t < 128) e[t] = ent_emb[(long)start_ent[b]*E + t];
        __syncthreads();
        float acc = 0.f;
        #pragma unroll
        for (int tile=0; tile<4; ++tile){
            #pragma unroll
            for (int ch=0; ch<16; ++ch){
                int idx = ch*256 + t;
                int jj = idx & 31, hh = idx >> 5;
                wt[hh][jj] = hW[hh*128 + tile*32 + jj];
            }
            __syncthreads();
            if (t < 128) {
                #pragma unroll
                for (int jj=0;jj<32;jj++) acc += wt[t][jj]*e[tile*32+jj];
            }
            __syncthreads();
        }
        if (t < 128) {
            float v = lrelu(acc + hb[t]);
            si[t] = v;
            init_out[b*128+t] = v;
        }
        __syncthreads();
        float acc2 = 0.f;
        #pragma unroll
        for (int tile=0; tile<4; ++tile){
            #pragma unroll
            for (int ch=0; ch<16; ++ch){
                int idx = ch*256 + t;
                int jj = idx & 31, hh = idx >> 5;
                wt[hh][jj] = passW[hh*256 + tile*32 + jj];
            }
            __syncthreads();
            if (t < 128) {
                #pragma unroll
                for (int jj=0;jj<32;jj++) acc2 += wt[t][jj]*si[tile*32+jj];
            }
            __syncthreads();
        }
        if (t < 128) wninit_out[b*128+t] = acc2;
    }
}

// =====================================================================
// K_B: upd = lrelu(hb + alpha*wninit[b] + beta*passb + X @ Wcat^T), MFMA,
// swizzled Wcat_f (frag-order, coalesced loads hoisted to registers)
// =====================================================================
__global__ void k_updg(const unsigned short* __restrict__ Xg, const float* __restrict__ ab,
                       const unsigned short* __restrict__ Wcatf,
                       const float* __restrict__ hb_, const float* __restrict__ passb,
                       const float* __restrict__ wninit,
                       float* __restrict__ upd){
    int b = blockIdx.x;
    int t = threadIdx.x;          // 0..255
    __shared__ __align__(16) unsigned short Xs[32][264];
    __shared__ float wni[128];
    __shared__ float sab[64];
    #pragma unroll
    for (int it = 0; it < 4; it++) {
        int idx = it*256 + t;
        int r = idx >> 5;
        int cc = (idx & 31) * 8;
        *(short8*)&Xs[r][cc] = *(const short8*)&Xg[((long)b*32 + r)*256 + cc];
    }
    if (t < 128) wni[t] = wninit[b*128 + t];
    else if (t < 192) sab[t-128] = ab[b*64 + (t-128)];

    int w    = t >> 6;
    int lane = t & 63;
    int l16  = lane & 15;
    int lhi  = lane >> 4;
    int hbase = w*32;

    // hoisted coalesced B-frag loads (frag-order layout)
    short8 bw[8][2];
    #pragma unroll
    for (int ks = 0; ks < 8; ks++) {
        #pragma unroll
        for (int ct = 0; ct < 2; ct++)
            bw[ks][ct] = *(const short8*)&Wcatf[((((w*8+ks)*2+ct)*64) + lane)*8];
    }
    __syncthreads();

    f32x4 acc[2][2];
    #pragma unroll
    for (int rt=0;rt<2;rt++)
        #pragma unroll
        for (int ct=0;ct<2;ct++)
            acc[rt][ct] = (f32x4){0.f,0.f,0.f,0.f};

    #pragma unroll
    for (int ks = 0; ks < 8; ks++) {
        int kof = ks*32 + lhi*8;
        short8 a0 = *(const short8*)&Xs[l16][kof];
        short8 a1 = *(const short8*)&Xs[16 + l16][kof];
        acc[0][0] = __builtin_amdgcn_mfma_f32_16x16x32_bf16(a0, bw[ks][0], acc[0][0], 0, 0, 0);
        acc[0][1] = __builtin_amdgcn_mfma_f32_16x16x32_bf16(a0, bw[ks][1], acc[0][1], 0, 0, 0);
        acc[1][0] = __builtin_amdgcn_mfma_f32_16x16x32_bf16(a1, bw[ks][0], acc[1][0], 0, 0, 0);
        acc[1][1] = __builtin_amdgcn_mfma_f32_16x16x32_bf16(a1, bw[ks][1], acc[1][1], 0, 0, 0);
    }

    int h0 = hbase + l16, h1 = hbase + 16 + l16;
    float hb0 = hb_[h0], hb1 = hb_[h1];
    float pb0 = passb[h0], pb1 = passb[h1];
    float w0 = wni[h0],  w1 = wni[h1];
    #pragma unroll
    for (int rt=0; rt<2; rt++) {
        #pragma unroll
        for (int i=0;i<4;i++) {
            int r = rt*16 + 4*lhi + i;
            float al = sab[r*2], be = sab[r*2+1];
            upd[((long)b*32 + r)*128 + h0] = lrelu(hb0 + al*w0 + be*pb0 + acc[rt][0][i]);
            upd[((long)b*32 + r)*128 + h1] = lrelu(hb1 + al*w1 + be*pb1 + acc[rt][1][i]);
        }
    }
}

// =====================================================================
// K_C: state + thresh; one block per b, 128 threads; LDS-tiled nexthop_W
// =====================================================================
__global__ void k_state(const int* __restrict__ currents, const int* __restrict__ map,
                        const float* __restrict__ init, const float* __restrict__ upd,
                        const float* __restrict__ query,
                        const float* __restrict__ nW, const float* __restrict__ nb,
                        const float* __restrict__ gW, const float* __restrict__ gb,
                        float* __restrict__ state, float* __restrict__ out){
    int b = blockIdx.x, t = threadIdx.x;  // 128
    __shared__ float cc[H+Q];
    __shared__ float wt[128][33];
    __shared__ float wsum[2];
    int mv = map[b*NSLOT + currents[b]];
    float cv = 0.f;
    if (mv == -1) cv = init[b*H+t];
    else if (mv >= 0) cv = upd[((long)b*K+mv)*H + t];
    cc[t] = cv;
    cc[H+t] = query[b*Q+t];
    __syncthreads();
    // thresh
    float tv = gW[t]*cc[t] + gW[H+t]*cc[H+t];
    for (int off=32; off>0; off>>=1) tv += __shfl_down(tv, off);
    if ((t&63)==0) wsum[t>>6] = tv;
    // matvec, 8 LDS tiles of nW (128x32, pad 33)
    float acc = 0.f;
    #pragma unroll
    for (int tile=0; tile<8; ++tile){
        #pragma unroll
        for (int ch=0; ch<32; ++ch){
            int idx = ch*128 + t;
            int jj = idx & 31, hh = idx >> 5;
            wt[hh][jj] = nW[hh*256 + tile*32 + jj];
        }
        __syncthreads();
        #pragma unroll
        for (int jj=0;jj<32;jj++) acc += wt[t][jj]*cc[tile*32+jj];
        __syncthreads();
    }
    state[b*H+t] = lrelu(acc + nb[t]);
    if (t==0) out[b*(MN+1) + MN] = wsum[0] + wsum[1] + gb[0];
}

// =====================================================================
// K_D: candidate linear via bf16 MFMA (frag-order Wf, register-hoisted)
//      + fused lrelu*state score
// =====================================================================
__global__ void k_cand(const int* __restrict__ cnodes, const int* __restrict__ cents,
                       const int* __restrict__ crels, const int* __restrict__ cmask,
                       const int* __restrict__ map,
                       const float* __restrict__ init, const float* __restrict__ upd,
                       const float* __restrict__ ent_emb, const float* __restrict__ rel_emb,
                       const unsigned short* __restrict__ Wf, const float* __restrict__ cb,
                       const float* __restrict__ state,
                       float* __restrict__ out){
    int blk = blockIdx.x;
    int b  = blk >> 3;
    int c0 = (blk & 7) * CTILE;
    int t  = threadIdx.x;         // 0..255

    __shared__ __align__(16) unsigned short Xb[CTILE][XPAD];
    __shared__ float sscore[4][CTILE];
    __shared__ int sce[CTILE], scr[CTILE], smv[CTILE];

    // ---- index resolution ----
    if (t < CTILE) {
        int row = b*MN + c0 + t;
        int cn = cnodes[row];
        sce[t] = cents[row];
        scr[t] = crels[row];
        smv[t] = map[b*NSLOT + cn];
    }
    __syncthreads();

    // ---- parallel staging: 8 candidates in flight, float4/lane ----
    {
        int c8 = t >> 5;
        int q  = t & 31;
        #pragma unroll
        for (int i = 0; i < 4; i++) {
            int c = i*8 + c8;
            int mv = smv[c];
            float4 nv = {0.f,0.f,0.f,0.f};
            if (mv == -1)      nv = *(const float4*)&init[b*H + q*4];
            else if (mv >= 0)  nv = *(const float4*)&upd[((long)b*K+mv)*H + q*4];
            float4 ev = *(const float4*)&ent_emb[(long)sce[c]*E + q*4];
            float4 rv = *(const float4*)&rel_emb[(long)scr[c]*E + q*4];
            *(short4b*)&Xb[c][q*4]        = pack4(nv);
            *(short4b*)&Xb[c][128 + q*4]  = pack4(ev);
            *(short4b*)&Xb[c][256 + q*4]  = pack4(rv);
        }
    }

    int w    = t >> 6;
    int lane = t & 63;
    int l16  = lane & 15;
    int lhi  = lane >> 4;

    // ---- hoisted coalesced W-frag loads (overlap the barrier wait) ----
    short8 bw[12][2];
    #pragma unroll
    for (int ks = 0; ks < 12; ks++) {
        #pragma unroll
        for (int ct = 0; ct < 2; ct++)
            bw[ks][ct] = *(const short8*)&Wf[((((w*12+ks)*2+ct)*64) + lane)*8];
    }
    float s0 = state[b*H + w*32 + l16];
    float s1 = state[b*H + w*32 + 16 + l16];
    float cb0 = cb[w*32 + l16];
    float cb1 = cb[w*32 + 16 + l16];
    __syncthreads();

    // ---- MFMA: C[32 cands][128 h] = X(32x384) @ W^T(384x128) ----
    f32x4 acc[2][2];
    #pragma unroll
    for (int rt=0;rt<2;rt++)
        #pragma unroll
        for (int ct=0;ct<2;ct++)
            acc[rt][ct] = (f32x4){0.f,0.f,0.f,0.f};

    #pragma unroll
    for (int ks = 0; ks < 12; ks++) {
        int kof = ks*32 + lhi*8;
        short8 a0 = *(const short8*)&Xb[l16][kof];
        short8 a1 = *(const short8*)&Xb[16 + l16][kof];
        acc[0][0] = __builtin_amdgcn_mfma_f32_16x16x32_bf16(a0, bw[ks][0], acc[0][0], 0, 0, 0);
        acc[0][1] = __builtin_amdgcn_mfma_f32_16x16x32_bf16(a0, bw[ks][1], acc[0][1], 0, 0, 0);
        acc[1][0] = __builtin_amdgcn_mfma_f32_16x16x32_bf16(a1, bw[ks][0], acc[1][0], 0, 0, 0);
        acc[1][1] = __builtin_amdgcn_mfma_f32_16x16x32_bf16(a1, bw[ks][1], acc[1][1], 0, 0, 0);
    }

    // ---- epilogue ----
    #pragma unroll
    for (int rt=0; rt<2; rt++) {
        float ps[4];
        #pragma unroll
        for (int i=0;i<4;i++)
            ps[i] = lrelu(acc[rt][0][i] + cb0)*s0 + lrelu(acc[rt][1][i] + cb1)*s1;
        #pragma unroll
        for (int msk=1; msk<16; msk<<=1) {
            #pragma unroll
            for (int i=0;i<4;i++) ps[i] += __shfl_xor(ps[i], msk);
        }
        if (l16 == 0) {
            #pragma unroll
            for (int i=0;i<4;i++)
                sscore[w][rt*16 + 4*lhi + i] = ps[i];
        }
    }
    __syncthreads();

    if (t < CTILE) {
        int row = b*MN + c0 + t;
        float s = (sscore[0][t] + sscore[1][t] + sscore[2][t] + sscore[3][t])
                  * 0.08838834764831845f;  // 1/sqrt(128)
        out[b*(MN+1) + c0 + t] = cmask[row] ? s : -100000.0f;
    }
}

extern "C" void kernel_launch(void* const* d_in, const int* in_sizes, int n_in,
                              void* d_out, int out_size, void* d_ws, size_t ws_size,
                              hipStream_t stream){
    (void)in_sizes; (void)n_in; (void)out_size; (void)ws_size;
    const int* start_entities      = (const int*)d_in[0];
    const int* aims                = (const int*)d_in[1];
    const int* node_pos            = (const int*)d_in[2];
    const int* neighbor_nodes      = (const int*)d_in[3];
    const int* neighbor_relations  = (const int*)d_in[4];
    const int* neighbors_num       = (const int*)d_in[5];
    const int* currents            = (const int*)d_in[6];
    const int* candidate_nodes     = (const int*)d_in[7];
    const int* candidate_entities  = (const int*)d_in[8];
    const int* candidate_relations = (const int*)d_in[9];
    const int* candidate_masks     = (const int*)d_in[10];
    const float* entity_emb   = (const float*)d_in[11];
    const float* relation_emb = (const float*)d_in[12];
    const float* hidden_W     = (const float*)d_in[13];
    const float* hidden_b     = (const float*)d_in[14];
    const float* pass_W       = (const float*)d_in[15];
    const float* pass_b       = (const float*)d_in[16];
    const float* nexthop_W    = (const float*)d_in[17];
    const float* nexthop_b    = (const float*)d_in[18];
    const float* candidate_W  = (const float*)d_in[19];
    const float* candidate_b  = (const float*)d_in[20];
    const float* gate_W       = (const float*)d_in[21];
    const float* gate_b       = (const float*)d_in[22];
    const float* query        = (const float*)d_in[23];
    float* out = (float*)d_out;

    float* ws     = (float*)d_ws;
    float* init   = ws;                        // B*H
    float* wninit = init + B*H;                // B*H
    float* upd    = wninit + B*H;              // B*K*H
    float* state  = upd + (long)B*K*H;         // B*H
    float* ab     = state + B*H;               // B*K*2
    int*   map    = (int*)(ab + B*K*2);        // B*NSLOT
    unsigned short* Wf    = (unsigned short*)(map + B*NSLOT);  // 4*12*2*64*8 = 49152
    unsigned short* Wcatf = Wf + 49152;                         // 4*8*2*64*8 = 32768
    unsigned short* Xg    = Wcatf + 32768;                      // B*K*256

    k_gprep<<<B*K, 256, 0, stream>>>(aims, neighbor_nodes, neighbor_relations, neighbors_num,
                                     start_entities, node_pos, entity_emb, relation_emb,
                                     hidden_W, hidden_b, pass_W, candidate_W,
                                     Xg, ab, map, init, wninit, Wf, Wcatf);
    k_updg<<<B, 256, 0, stream>>>(Xg, ab, Wcatf, hidden_b, pass_b, wninit, upd);
    k_state<<<B, 128, 0, stream>>>(currents, map, init, upd, query,
                                   nexthop_W, nexthop_b, gate_W, gate_b, state, out);
    k_cand<<<B*(MN/CTILE), 256, 0, stream>>>(candidate_nodes, candidate_entities,
                                             candidate_relations, candidate_masks,
                                             map, init, upd, entity_emb, relation_emb,
                                             Wf, candidate_b, state, out);
}

// Round 7
// 55.895 us; speedup vs baseline: 1.9954x; 1.9954x over previous
//
#include <hip/hip_runtime.h>

#define B 256
#define K 32
#define M 64
#define MN 256
#define E 128
#define H 128
#define Q 128
#define NSLOT 258   // NNODES+2
#define CTILE 32
#define XPAD 392    // 384 + 8 bf16 pad

typedef __attribute__((ext_vector_type(8))) short short8;
typedef __attribute__((ext_vector_type(4))) short short4b;
typedef __attribute__((ext_vector_type(4))) float f32x4;

__device__ __forceinline__ float lrelu(float x){ return x >= 0.f ? x : 0.01f*x; }

// fp32 -> bf16 RTNE
__device__ __forceinline__ unsigned short f2bf(float f){
    unsigned int u = __float_as_uint(f);
    unsigned int r = u + 0x7FFFu + ((u >> 16) & 1u);
    return (unsigned short)(r >> 16);
}

__device__ __forceinline__ short4b pack4(float4 v){
    short4b r;
    r.x = (short)f2bf(v.x); r.y = (short)f2bf(v.y);
    r.z = (short)f2bf(v.z); r.w = (short)f2bf(v.w);
    return r;
}

// =====================================================================
// K_P: all small prep in one launch, role by blockIdx (832 blocks, 256 thr)
//  blk <  256 : init[b] + wninit[b]           (b = blk)
//  blk <  512 : map[b]                        (b = blk-256)
//  blk <  704 : Wf  frag-order swizzle slice  (i = (blk-512)*256+t, n=49152)
//  blk <  832 : Wcatf frag-order swizzle slice(i = (blk-704)*256+t, n=32768)
// =====================================================================
__global__ void k_prep(const int* __restrict__ start_ent, const int* __restrict__ node_pos,
                       const float* __restrict__ ent_emb,
                       const float* __restrict__ hW, const float* __restrict__ hb,
                       const float* __restrict__ passW, const float* __restrict__ candW,
                       int* __restrict__ map,
                       float* __restrict__ init_out, float* __restrict__ wninit_out,
                       unsigned short* __restrict__ Wf, unsigned short* __restrict__ Wcatf){
    int blk = blockIdx.x, t = threadIdx.x;
    if (blk < 256) {
        int b = blk;
        __shared__ float e[E];
        __shared__ float si[H];
        if (t < 128) e[t] = ent_emb[(long)start_ent[b]*E + t];
        __syncthreads();
        if (t < 128) {
            float acc = hb[t];
            #pragma unroll 8
            for (int j=0;j<E;j++) acc += hW[t*E+j]*e[j];
            float v = lrelu(acc);
            si[t] = v;
            init_out[b*H+t] = v;
        }
        __syncthreads();
        if (t < 128) {
            float acc2 = 0.f;
            #pragma unroll 8
            for (int j=0;j<H;j++) acc2 += passW[t*(H+E)+j]*si[j];
            wninit_out[b*H+t] = acc2;
        }
    } else if (blk < 512) {
        int b = blk - 256;
        for (int i=t;i<NSLOT;i+=256) map[b*NSLOT+i] = -2;
        __syncthreads();
        if (t==0) map[b*NSLOT+0] = -1;
        __syncthreads();
        if (t<K) map[b*NSLOT + node_pos[b*K+t]] = t;
    } else if (blk < 704) {
        // Wf: layout i = ((w*12+ks)*2 + ct)*512 + lane*8 + j
        int i = (blk-512)*256 + t;      // < 49152
        int j = i & 7;
        int l = (i >> 3) & 63;
        int ct = (i >> 9) & 1;
        int r = i >> 10;                // 0..47
        int ks = r % 12, w = r / 12;
        int row = w*32 + ct*16 + (l & 15);
        int col = ks*32 + (l >> 4)*8 + j;
        Wf[i] = f2bf(candW[row*384 + col]);
    } else {
        // Wcatf: i = ((w*8+ks)*2 + ct)*512 + lane*8 + j ; Wcat[h][c]=c<128?passW[h][128+c]:hW[h][c-128]
        int i = (blk-704)*256 + t;      // < 32768
        int j = i & 7;
        int l = (i >> 3) & 63;
        int ct = (i >> 9) & 1;
        int r = i >> 10;                // 0..31
        int ks = r & 7, w = r >> 3;
        int row = w*32 + ct*16 + (l & 15);
        int col = ks*32 + (l >> 4)*8 + j;
        float v = (col < 128) ? passW[row*256 + 128 + col] : hW[row*128 + (col-128)];
        Wcatf[i] = f2bf(v);
    }
}

// =====================================================================
// K_G: per (b,k): parallel rel-row gather-sum, c0 count, bf16 X row + ab
// (lean LDS: ~4.4 KB -> full occupancy)
// =====================================================================
__global__ void k_gather(const int* __restrict__ aims, const int* __restrict__ nbr_nodes,
                         const int* __restrict__ nbr_rels, const int* __restrict__ nbr_num,
                         const float* __restrict__ ent_emb, const float* __restrict__ rel_emb,
                         unsigned short* __restrict__ Xg,   // (B*K) x 256 bf16
                         float* __restrict__ ab){           // (B*K) x 2
    int bk = blockIdx.x;
    int t = threadIdx.x;          // 0..255
    int num = nbr_num[bk];
    __shared__ int sidx[M];
    __shared__ int sc0;
    __shared__ float red[8][128];
    if (t < 64) sidx[t] = nbr_rels[(long)bk*M + t];
    if (t >= 64 && t < 128) {     // exactly wave 1
        int m = t - 64;
        bool flag = (m < num) && (nbr_nodes[(long)bk*M + m] == 0);
        unsigned long long mask = __ballot(flag);
        if (m == 0) sc0 = (int)__popcll(mask);
    }
    if (t >= 128) {               // waves 2,3: aim entity row -> X[128..255]
        int d = t - 128;
        Xg[(long)bk*256 + 128 + d] = f2bf(ent_emb[(long)aims[bk]*E + d]);
    }
    __syncthreads();
    int mg = t >> 5, q = t & 31;
    float4 acc = {0.f,0.f,0.f,0.f};
    for (int m = mg; m < num; m += 8) {
        const float4 v = *(const float4*)&rel_emb[(long)sidx[m]*E + q*4];
        acc.x += v.x; acc.y += v.y; acc.z += v.z; acc.w += v.w;
    }
    red[mg][q*4+0] = acc.x; red[mg][q*4+1] = acc.y;
    red[mg][q*4+2] = acc.z; red[mg][q*4+3] = acc.w;
    __syncthreads();
    float denom = (float)(num > 0 ? num : 1);
    if (t < 128) {
        float s = 0.f;
        #pragma unroll
        for (int g=0; g<8; g++) s += red[g][t];
        Xg[(long)bk*256 + t] = f2bf(s / denom);
    }
    if (t == 0) {
        ab[bk*2+0] = (float)sc0 / denom;
        ab[bk*2+1] = (float)num / denom;
    }
}

// =====================================================================
// K_B: upd = lrelu(hb + alpha*wninit[b] + beta*passb + X @ Wcat^T), MFMA,
// frag-order Wcatf (coalesced loads hoisted to registers)
// =====================================================================
__global__ void k_updg(const unsigned short* __restrict__ Xg, const float* __restrict__ ab,
                       const unsigned short* __restrict__ Wcatf,
                       const float* __restrict__ hb_, const float* __restrict__ passb,
                       const float* __restrict__ wninit,
                       float* __restrict__ upd){
    int b = blockIdx.x;
    int t = threadIdx.x;          // 0..255
    __shared__ __align__(16) unsigned short Xs[32][264];
    __shared__ float wni[128];
    __shared__ float sab[64];
    #pragma unroll
    for (int it = 0; it < 4; it++) {
        int idx = it*256 + t;
        int r = idx >> 5;
        int cc = (idx & 31) * 8;
        *(short8*)&Xs[r][cc] = *(const short8*)&Xg[((long)b*32 + r)*256 + cc];
    }
    if (t < 128) wni[t] = wninit[b*128 + t];
    else if (t < 192) sab[t-128] = ab[b*64 + (t-128)];

    int w    = t >> 6;
    int lane = t & 63;
    int l16  = lane & 15;
    int lhi  = lane >> 4;
    int hbase = w*32;

    short8 bw[8][2];
    #pragma unroll
    for (int ks = 0; ks < 8; ks++) {
        #pragma unroll
        for (int ct = 0; ct < 2; ct++)
            bw[ks][ct] = *(const short8*)&Wcatf[((((w*8+ks)*2+ct)*64) + lane)*8];
    }
    __syncthreads();

    f32x4 acc[2][2];
    #pragma unroll
    for (int rt=0;rt<2;rt++)
        #pragma unroll
        for (int ct=0;ct<2;ct++)
            acc[rt][ct] = (f32x4){0.f,0.f,0.f,0.f};

    #pragma unroll
    for (int ks = 0; ks < 8; ks++) {
        int kof = ks*32 + lhi*8;
        short8 a0 = *(const short8*)&Xs[l16][kof];
        short8 a1 = *(const short8*)&Xs[16 + l16][kof];
        acc[0][0] = __builtin_amdgcn_mfma_f32_16x16x32_bf16(a0, bw[ks][0], acc[0][0], 0, 0, 0);
        acc[0][1] = __builtin_amdgcn_mfma_f32_16x16x32_bf16(a0, bw[ks][1], acc[0][1], 0, 0, 0);
        acc[1][0] = __builtin_amdgcn_mfma_f32_16x16x32_bf16(a1, bw[ks][0], acc[1][0], 0, 0, 0);
        acc[1][1] = __builtin_amdgcn_mfma_f32_16x16x32_bf16(a1, bw[ks][1], acc[1][1], 0, 0, 0);
    }

    int h0 = hbase + l16, h1 = hbase + 16 + l16;
    float hb0 = hb_[h0], hb1 = hb_[h1];
    float pb0 = passb[h0], pb1 = passb[h1];
    float w0 = wni[h0],  w1 = wni[h1];
    #pragma unroll
    for (int rt=0; rt<2; rt++) {
        #pragma unroll
        for (int i=0;i<4;i++) {
            int r = rt*16 + 4*lhi + i;
            float al = sab[r*2], be = sab[r*2+1];
            upd[((long)b*32 + r)*128 + h0] = lrelu(hb0 + al*w0 + be*pb0 + acc[rt][0][i]);
            upd[((long)b*32 + r)*128 + h1] = lrelu(hb1 + al*w1 + be*pb1 + acc[rt][1][i]);
        }
    }
}

// =====================================================================
// K_C: state + thresh; one block per b, 128 threads
// =====================================================================
__global__ void k_state(const int* __restrict__ currents, const int* __restrict__ map,
                        const float* __restrict__ init, const float* __restrict__ upd,
                        const float* __restrict__ query,
                        const float* __restrict__ nW, const float* __restrict__ nb,
                        const float* __restrict__ gW, const float* __restrict__ gb,
                        float* __restrict__ state, float* __restrict__ out){
    int b = blockIdx.x, t = threadIdx.x;  // 128
    __shared__ float cc[H+Q];
    __shared__ float wsum[2];
    int mv = map[b*NSLOT + currents[b]];
    float cv = 0.f;
    if (mv == -1) cv = init[b*H+t];
    else if (mv >= 0) cv = upd[((long)b*K+mv)*H + t];
    cc[t] = cv;
    cc[H+t] = query[b*Q+t];
    __syncthreads();
    float acc = nb[t];
    #pragma unroll 8
    for (int j=0;j<H+Q;j++) acc += nW[t*(H+Q)+j]*cc[j];
    state[b*H+t] = lrelu(acc);
    float tv = gW[t]*cc[t] + gW[H+t]*cc[H+t];
    for (int off=32; off>0; off>>=1) tv += __shfl_down(tv, off);
    if ((t&63)==0) wsum[t>>6] = tv;
    __syncthreads();
    if (t==0) out[b*(MN+1) + MN] = wsum[0] + wsum[1] + gb[0];
}

// =====================================================================
// K_D: candidate linear via bf16 MFMA (frag-order Wf, register-hoisted)
//      + fused lrelu*state score
// =====================================================================
__global__ void k_cand(const int* __restrict__ cnodes, const int* __restrict__ cents,
                       const int* __restrict__ crels, const int* __restrict__ cmask,
                       const int* __restrict__ map,
                       const float* __restrict__ init, const float* __restrict__ upd,
                       const float* __restrict__ ent_emb, const float* __restrict__ rel_emb,
                       const unsigned short* __restrict__ Wf, const float* __restrict__ cb,
                       const float* __restrict__ state,
                       float* __restrict__ out){
    int blk = blockIdx.x;
    int b  = blk >> 3;
    int c0 = (blk & 7) * CTILE;
    int t  = threadIdx.x;         // 0..255

    __shared__ __align__(16) unsigned short Xb[CTILE][XPAD];
    __shared__ float sscore[4][CTILE];
    __shared__ int sce[CTILE], scr[CTILE], smv[CTILE];

    if (t < CTILE) {
        int row = b*MN + c0 + t;
        int cn = cnodes[row];
        sce[t] = cents[row];
        scr[t] = crels[row];
        smv[t] = map[b*NSLOT + cn];
    }
    __syncthreads();

    {
        int c8 = t >> 5;
        int q  = t & 31;
        #pragma unroll
        for (int i = 0; i < 4; i++) {
            int c = i*8 + c8;
            int mv = smv[c];
            float4 nv = {0.f,0.f,0.f,0.f};
            if (mv == -1)      nv = *(const float4*)&init[b*H + q*4];
            else if (mv >= 0)  nv = *(const float4*)&upd[((long)b*K+mv)*H + q*4];
            float4 ev = *(const float4*)&ent_emb[(long)sce[c]*E + q*4];
            float4 rv = *(const float4*)&rel_emb[(long)scr[c]*E + q*4];
            *(short4b*)&Xb[c][q*4]        = pack4(nv);
            *(short4b*)&Xb[c][128 + q*4]  = pack4(ev);
            *(short4b*)&Xb[c][256 + q*4]  = pack4(rv);
        }
    }

    int w    = t >> 6;
    int lane = t & 63;
    int l16  = lane & 15;
    int lhi  = lane >> 4;

    short8 bw[12][2];
    #pragma unroll
    for (int ks = 0; ks < 12; ks++) {
        #pragma unroll
        for (int ct = 0; ct < 2; ct++)
            bw[ks][ct] = *(const short8*)&Wf[((((w*12+ks)*2+ct)*64) + lane)*8];
    }
    float s0 = state[b*H + w*32 + l16];
    float s1 = state[b*H + w*32 + 16 + l16];
    float cb0 = cb[w*32 + l16];
    float cb1 = cb[w*32 + 16 + l16];
    __syncthreads();

    f32x4 acc[2][2];
    #pragma unroll
    for (int rt=0;rt<2;rt++)
        #pragma unroll
        for (int ct=0;ct<2;ct++)
            acc[rt][ct] = (f32x4){0.f,0.f,0.f,0.f};

    #pragma unroll
    for (int ks = 0; ks < 12; ks++) {
        int kof = ks*32 + lhi*8;
        short8 a0 = *(const short8*)&Xb[l16][kof];
        short8 a1 = *(const short8*)&Xb[16 + l16][kof];
        acc[0][0] = __builtin_amdgcn_mfma_f32_16x16x32_bf16(a0, bw[ks][0], acc[0][0], 0, 0, 0);
        acc[0][1] = __builtin_amdgcn_mfma_f32_16x16x32_bf16(a0, bw[ks][1], acc[0][1], 0, 0, 0);
        acc[1][0] = __builtin_amdgcn_mfma_f32_16x16x32_bf16(a1, bw[ks][0], acc[1][0], 0, 0, 0);
        acc[1][1] = __builtin_amdgcn_mfma_f32_16x16x32_bf16(a1, bw[ks][1], acc[1][1], 0, 0, 0);
    }

    #pragma unroll
    for (int rt=0; rt<2; rt++) {
        float ps[4];
        #pragma unroll
        for (int i=0;i<4;i++)
            ps[i] = lrelu(acc[rt][0][i] + cb0)*s0 + lrelu(acc[rt][1][i] + cb1)*s1;
        #pragma unroll
        for (int msk=1; msk<16; msk<<=1) {
            #pragma unroll
            for (int i=0;i<4;i++) ps[i] += __shfl_xor(ps[i], msk);
        }
        if (l16 == 0) {
            #pragma unroll
            for (int i=0;i<4;i++)
                sscore[w][rt*16 + 4*lhi + i] = ps[i];
        }
    }
    __syncthreads();

    if (t < CTILE) {
        int row = b*MN + c0 + t;
        float s = (sscore[0][t] + sscore[1][t] + sscore[2][t] + sscore[3][t])
                  * 0.08838834764831845f;  // 1/sqrt(128)
        out[b*(MN+1) + c0 + t] = cmask[row] ? s : -100000.0f;
    }
}

extern "C" void kernel_launch(void* const* d_in, const int* in_sizes, int n_in,
                              void* d_out, int out_size, void* d_ws, size_t ws_size,
                              hipStream_t stream){
    (void)in_sizes; (void)n_in; (void)out_size; (void)ws_size;
    const int* start_entities      = (const int*)d_in[0];
    const int* aims                = (const int*)d_in[1];
    const int* node_pos            = (const int*)d_in[2];
    const int* neighbor_nodes      = (const int*)d_in[3];
    const int* neighbor_relations  = (const int*)d_in[4];
    const int* neighbors_num       = (const int*)d_in[5];
    const int* currents            = (const int*)d_in[6];
    const int* candidate_nodes     = (const int*)d_in[7];
    const int* candidate_entities  = (const int*)d_in[8];
    const int* candidate_relations = (const int*)d_in[9];
    const int* candidate_masks     = (const int*)d_in[10];
    const float* entity_emb   = (const float*)d_in[11];
    const float* relation_emb = (const float*)d_in[12];
    const float* hidden_W     = (const float*)d_in[13];
    const float* hidden_b     = (const float*)d_in[14];
    const float* pass_W       = (const float*)d_in[15];
    const float* pass_b       = (const float*)d_in[16];
    const float* nexthop_W    = (const float*)d_in[17];
    const float* nexthop_b    = (const float*)d_in[18];
    const float* candidate_W  = (const float*)d_in[19];
    const float* candidate_b  = (const float*)d_in[20];
    const float* gate_W       = (const float*)d_in[21];
    const float* gate_b       = (const float*)d_in[22];
    const float* query        = (const float*)d_in[23];
    float* out = (float*)d_out;

    float* ws     = (float*)d_ws;
    float* init   = ws;                        // B*H
    float* wninit = init + B*H;                // B*H
    float* upd    = wninit + B*H;              // B*K*H
    float* state  = upd + (long)B*K*H;         // B*H
    float* ab     = state + B*H;               // B*K*2
    int*   map    = (int*)(ab + B*K*2);        // B*NSLOT
    unsigned short* Wf    = (unsigned short*)(map + B*NSLOT);  // 49152
    unsigned short* Wcatf = Wf + 49152;                         // 32768
    unsigned short* Xg    = Wcatf + 32768;                      // B*K*256

    k_prep<<<832, 256, 0, stream>>>(start_entities, node_pos, entity_emb,
                                    hidden_W, hidden_b, pass_W, candidate_W,
                                    map, init, wninit, Wf, Wcatf);
    k_gather<<<B*K, 256, 0, stream>>>(aims, neighbor_nodes, neighbor_relations, neighbors_num,
                                      entity_emb, relation_emb, Xg, ab);
    k_updg<<<B, 256, 0, stream>>>(Xg, ab, Wcatf, hidden_b, pass_b, wninit, upd);
    k_state<<<B, 128, 0, stream>>>(currents, map, init, upd, query,
                                   nexthop_W, nexthop_b, gate_W, gate_b, state, out);
    k_cand<<<B*(MN/CTILE), 256, 0, stream>>>(candidate_nodes, candidate_entities,
                                             candidate_relations, candidate_masks,
                                             map, init, upd, entity_emb, relation_emb,
                                             Wf, candidate_b, state, out);
}